// Round 4
// baseline (234.438 us; speedup 1.0000x reference)
//
#include <hip/hip_runtime.h>

// OverlappingEdgeProcessor: x (4,6,16,512,512) f32.
// Strategy: branch-free batched copy kernel (out = in, 403 MB each way,
// 4 independent loads in flight per wave-iteration, linear sweep) +
// tiny edge kernel overwriting only the 4-wide blend strips (~0.5%).
//
// Edge tables (verified passing in R1/R3), delta = ar_idx - er_idx (float4).
// Col strips (faces 0-3, w4=0 'L' / w4=127 'R'), er weights per element:
//   L: {0,1/3,2/3,1}   R: {1,2/3,1/3,0}
// Row strips (faces 0,2,4,5; top h=i / bottom h=508+i), uniform weight
//   t = i/3 (top) or (3-i)/3 (bottom) on er.
// Precedence: row blends win in corners -> col threads on faces 0,2 skip
// h in [0,4) u [508,512).

constexpr int W4 = 128;          // 512 floats / 4
constexpr int PLANE = 512 * W4;  // float4 per (b,f,c) plane = 65536
constexpr int FS = 16 * PLANE;   // face stride = 1048576 float4
constexpr int RO = 508 * W4;     // 508-row offset

__constant__ int kColDelta[4][2] = {
    {2 * FS + 127, 3 * FS - 127},
    {2 * FS + 127, 1 * FS - 127},
    {-1 * FS + 127, -2 * FS - 127},
    {-3 * FS + 127, -2 * FS - 127}};
__constant__ int kRowDelta[4][2] = {
    {4 * FS, 5 * FS - RO},
    {2 * FS + RO, 3 * FS},
    {-4 * FS, -2 * FS - RO},
    {-5 * FS + RO, -3 * FS}};
__constant__ int kRowFace[4] = {0, 2, 4, 5};

// Pure streaming copy: 12 batches of 4 strided float4 loads + 4 stores.
// Grid: 2048 blocks x 256 threads -> stride 524288; 25165824 / (4*524288)
// = 12 exact, no tail.
__global__ __launch_bounds__(256) void copy_kernel(
    const float4* __restrict__ in, float4* __restrict__ out, int total4) {
  const int S = gridDim.x * blockDim.x;
  int i = blockIdx.x * blockDim.x + threadIdx.x;
  for (; i + 3 * S < total4; i += 4 * S) {
    float4 a = in[i];
    float4 b = in[i + S];
    float4 c = in[i + 2 * S];
    float4 d = in[i + 3 * S];
    out[i] = a;
    out[i + S] = b;
    out[i + 2 * S] = c;
    out[i + 3 * S] = d;
  }
  for (; i < total4; i += S) out[i] = in[i];
}

__global__ __launch_bounds__(256) void edge_fix_kernel(
    const float4* __restrict__ in, float4* __restrict__ out) {
  const int id = blockIdx.x * blockDim.x + threadIdx.x;  // [0, 524288)
  const float inv3 = 1.0f / 3.0f;

  if (id < 262144) {
    // ---- column strips ----
    int cid = id;
    int h = cid & 511; cid >>= 9;
    int c = cid & 15;  cid >>= 4;
    int s = cid & 1;   cid >>= 1;
    int face = cid & 3;           // faces 0..3
    int b = cid >> 2;
    if ((face == 0 || face == 2) && (h < 4 || h >= 508)) return;  // row wins
    int idx = (b * 6 + face) * FS + c * PLANE + h * W4 + (s ? 127 : 0);
    float4 er = in[idx];
    float4 ar = in[idx + kColDelta[face][s]];
    float4 r;
    if (s == 0) {  // left: er w = {0,1/3,2/3,1}
      r = float4{ar.x, er.y * inv3 + ar.y * (2.f * inv3),
                 er.z * (2.f * inv3) + ar.z * inv3, er.w};
    } else {       // right: er w = {1,2/3,1/3,0}
      r = float4{er.x, er.y * (2.f * inv3) + ar.y * inv3,
                 er.z * inv3 + ar.z * (2.f * inv3), ar.w};
    }
    out[idx] = r;
  } else {
    // ---- row strips ----
    int rid = id - 262144;
    int w4 = rid & 127; rid >>= 7;
    int i = rid & 3;    rid >>= 2;
    int c = rid & 15;   rid >>= 4;
    int s = rid & 1;    rid >>= 1;
    int fr = rid & 3;
    int b = rid >> 2;
    int face = kRowFace[fr];
    int h = s ? 508 + i : i;
    int idx = (b * 6 + face) * FS + c * PLANE + h * W4 + w4;
    float t = (s ? (3 - i) : i) * inv3;
    float u = 1.0f - t;
    float4 er = in[idx];
    float4 ar = in[idx + kRowDelta[fr][s]];
    out[idx] = float4{er.x * t + ar.x * u, er.y * t + ar.y * u,
                      er.z * t + ar.z * u, er.w * t + ar.w * u};
  }
}

extern "C" void kernel_launch(void* const* d_in, const int* in_sizes, int n_in,
                              void* d_out, int out_size, void* d_ws,
                              size_t ws_size, hipStream_t stream) {
  const float4* in = (const float4*)d_in[0];
  float4* out = (float4*)d_out;
  int total4 = in_sizes[0] / 4;  // 25,165,824
  hipLaunchKernelGGL(copy_kernel, dim3(2048), dim3(256), 0, stream, in, out,
                     total4);
  hipLaunchKernelGGL(edge_fix_kernel, dim3(524288 / 256), dim3(256), 0,
                     stream, in, out);
}

// Round 5
// 160.269 us; speedup vs baseline: 1.4628x; 1.4628x over previous
//
#include <hip/hip_runtime.h>

// OverlappingEdgeProcessor: x (4,6,16,512,512) f32.
// Strategy: flattest-possible copy (one float4 per thread, no loop — the
// m13-µbench / fillBuffer structure that hits 6.3-7 TB/s) + tiny edge kernel
// overwriting only the 4-wide blend strips (~0.5% of elements).
//
// Edge tables (verified passing in R1/R3/R4), delta = ar_idx - er_idx (float4).
// Col strips (faces 0-3, w4=0 'L' / w4=127 'R'), er weights per element:
//   L: {0,1/3,2/3,1}   R: {1,2/3,1/3,0}
// Row strips (faces 0,2,4,5; top h=i / bottom h=508+i), uniform weight
//   t = i/3 (top) or (3-i)/3 (bottom) on er.
// Precedence: row blends win in corners -> col threads on faces 0,2 skip
// h in [0,4) u [508,512).

constexpr int W4 = 128;          // 512 floats / 4
constexpr int PLANE = 512 * W4;  // float4 per (b,f,c) plane = 65536
constexpr int FS = 16 * PLANE;   // face stride = 1048576 float4
constexpr int RO = 508 * W4;     // 508-row offset

__constant__ int kColDelta[4][2] = {
    {2 * FS + 127, 3 * FS - 127},
    {2 * FS + 127, 1 * FS - 127},
    {-1 * FS + 127, -2 * FS - 127},
    {-3 * FS + 127, -2 * FS - 127}};
__constant__ int kRowDelta[4][2] = {
    {4 * FS, 5 * FS - RO},
    {2 * FS + RO, 3 * FS},
    {-4 * FS, -2 * FS - RO},
    {-5 * FS + RO, -3 * FS}};
__constant__ int kRowFace[4] = {0, 2, 4, 5};

// One float4 per thread, no loop. 25,165,824 items / 256 = 98304 blocks.
__global__ __launch_bounds__(256) void copy_kernel(
    const float4* __restrict__ in, float4* __restrict__ out) {
  const int i = blockIdx.x * blockDim.x + threadIdx.x;
  out[i] = in[i];
}

__global__ __launch_bounds__(256) void edge_fix_kernel(
    const float4* __restrict__ in, float4* __restrict__ out) {
  const int id = blockIdx.x * blockDim.x + threadIdx.x;  // [0, 524288)
  const float inv3 = 1.0f / 3.0f;

  if (id < 262144) {
    // ---- column strips ----
    int cid = id;
    int h = cid & 511; cid >>= 9;
    int c = cid & 15;  cid >>= 4;
    int s = cid & 1;   cid >>= 1;
    int face = cid & 3;           // faces 0..3
    int b = cid >> 2;
    if ((face == 0 || face == 2) && (h < 4 || h >= 508)) return;  // row wins
    int idx = (b * 6 + face) * FS + c * PLANE + h * W4 + (s ? 127 : 0);
    float4 er = in[idx];
    float4 ar = in[idx + kColDelta[face][s]];
    float4 r;
    if (s == 0) {  // left: er w = {0,1/3,2/3,1}
      r = float4{ar.x, er.y * inv3 + ar.y * (2.f * inv3),
                 er.z * (2.f * inv3) + ar.z * inv3, er.w};
    } else {       // right: er w = {1,2/3,1/3,0}
      r = float4{er.x, er.y * (2.f * inv3) + ar.y * inv3,
                 er.z * inv3 + ar.z * (2.f * inv3), ar.w};
    }
    out[idx] = r;
  } else {
    // ---- row strips ----
    int rid = id - 262144;
    int w4 = rid & 127; rid >>= 7;
    int i = rid & 3;    rid >>= 2;
    int c = rid & 15;   rid >>= 4;
    int s = rid & 1;    rid >>= 1;
    int fr = rid & 3;
    int b = rid >> 2;
    int face = kRowFace[fr];
    int h = s ? 508 + i : i;
    int idx = (b * 6 + face) * FS + c * PLANE + h * W4 + w4;
    float t = (s ? (3 - i) : i) * inv3;
    float u = 1.0f - t;
    float4 er = in[idx];
    float4 ar = in[idx + kRowDelta[fr][s]];
    out[idx] = float4{er.x * t + ar.x * u, er.y * t + ar.y * u,
                      er.z * t + ar.z * u, er.w * t + ar.w * u};
  }
}

extern "C" void kernel_launch(void* const* d_in, const int* in_sizes, int n_in,
                              void* d_out, int out_size, void* d_ws,
                              size_t ws_size, hipStream_t stream) {
  const float4* in = (const float4*)d_in[0];
  float4* out = (float4*)d_out;
  int total4 = in_sizes[0] / 4;  // 25,165,824 = 98304 * 256
  hipLaunchKernelGGL(copy_kernel, dim3(total4 / 256), dim3(256), 0, stream,
                     in, out);
  hipLaunchKernelGGL(edge_fix_kernel, dim3(524288 / 256), dim3(256), 0,
                     stream, in, out);
}

// Round 7
// 145.635 us; speedup vs baseline: 1.6098x; 1.1005x over previous
//
#include <hip/hip_runtime.h>

// OverlappingEdgeProcessor: x (4,6,16,512,512) f32.
// Strategy (R5 structure + nontemporal hints):
//   1) flat copy, one float4 per thread, nontemporal load+store (pure
//      streaming; avoid L2 pollution on the 403 MB each-way stream)
//   2) tiny edge kernel overwriting only the 4-wide blend strips (~0.5%).
// NOTE: __builtin_nontemporal_* requires a native vector type, not
// HIP_vector_type -> use clang ext_vector_type(4).
//
// Edge tables (verified passing R1/R3/R4/R5), delta = ar_idx - er_idx (float4).
// Col strips (faces 0-3, w4=0 'L' / w4=127 'R'), er weights per element:
//   L: {0,1/3,2/3,1}   R: {1,2/3,1/3,0}
// Row strips (faces 0,2,4,5; top h=i / bottom h=508+i), uniform weight
//   t = i/3 (top) or (3-i)/3 (bottom) on er.
// Precedence: row blends win in corners -> col threads on faces 0,2 skip
// h in [0,4) u [508,512).

typedef float f4 __attribute__((ext_vector_type(4)));

constexpr int W4 = 128;          // 512 floats / 4
constexpr int PLANE = 512 * W4;  // float4 per (b,f,c) plane = 65536
constexpr int FS = 16 * PLANE;   // face stride = 1048576 float4
constexpr int RO = 508 * W4;     // 508-row offset

__constant__ int kColDelta[4][2] = {
    {2 * FS + 127, 3 * FS - 127},
    {2 * FS + 127, 1 * FS - 127},
    {-1 * FS + 127, -2 * FS - 127},
    {-3 * FS + 127, -2 * FS - 127}};
__constant__ int kRowDelta[4][2] = {
    {4 * FS, 5 * FS - RO},
    {2 * FS + RO, 3 * FS},
    {-4 * FS, -2 * FS - RO},
    {-5 * FS + RO, -3 * FS}};
__constant__ int kRowFace[4] = {0, 2, 4, 5};

// One float4 per thread, no loop, nontemporal both ways.
__global__ __launch_bounds__(256) void copy_kernel(
    const f4* __restrict__ in, f4* __restrict__ out) {
  const int i = blockIdx.x * blockDim.x + threadIdx.x;
  f4 v = __builtin_nontemporal_load(&in[i]);
  __builtin_nontemporal_store(v, &out[i]);
}

__global__ __launch_bounds__(256) void edge_fix_kernel(
    const f4* __restrict__ in, f4* __restrict__ out) {
  const int id = blockIdx.x * blockDim.x + threadIdx.x;  // [0, 524288)
  const float inv3 = 1.0f / 3.0f;

  if (id < 262144) {
    // ---- column strips ----
    int cid = id;
    int h = cid & 511; cid >>= 9;
    int c = cid & 15;  cid >>= 4;
    int s = cid & 1;   cid >>= 1;
    int face = cid & 3;           // faces 0..3
    int b = cid >> 2;
    if ((face == 0 || face == 2) && (h < 4 || h >= 508)) return;  // row wins
    int idx = (b * 6 + face) * FS + c * PLANE + h * W4 + (s ? 127 : 0);
    f4 er = in[idx];
    f4 ar = in[idx + kColDelta[face][s]];
    f4 r;
    if (s == 0) {  // left: er w = {0,1/3,2/3,1}
      r = f4{ar.x, er.y * inv3 + ar.y * (2.f * inv3),
             er.z * (2.f * inv3) + ar.z * inv3, er.w};
    } else {       // right: er w = {1,2/3,1/3,0}
      r = f4{er.x, er.y * (2.f * inv3) + ar.y * inv3,
             er.z * inv3 + ar.z * (2.f * inv3), ar.w};
    }
    __builtin_nontemporal_store(r, &out[idx]);
  } else {
    // ---- row strips ----
    int rid = id - 262144;
    int w4 = rid & 127; rid >>= 7;
    int i = rid & 3;    rid >>= 2;
    int c = rid & 15;   rid >>= 4;
    int s = rid & 1;    rid >>= 1;
    int fr = rid & 3;
    int b = rid >> 2;
    int face = kRowFace[fr];
    int h = s ? 508 + i : i;
    int idx = (b * 6 + face) * FS + c * PLANE + h * W4 + w4;
    float t = (s ? (3 - i) : i) * inv3;
    float u = 1.0f - t;
    f4 er = in[idx];
    f4 ar = in[idx + kRowDelta[fr][s]];
    f4 r = er * t + ar * u;
    __builtin_nontemporal_store(r, &out[idx]);
  }
}

extern "C" void kernel_launch(void* const* d_in, const int* in_sizes, int n_in,
                              void* d_out, int out_size, void* d_ws,
                              size_t ws_size, hipStream_t stream) {
  const f4* in = (const f4*)d_in[0];
  f4* out = (f4*)d_out;
  int total4 = in_sizes[0] / 4;  // 25,165,824 = 98304 * 256
  hipLaunchKernelGGL(copy_kernel, dim3(total4 / 256), dim3(256), 0, stream,
                     in, out);
  hipLaunchKernelGGL(edge_fix_kernel, dim3(524288 / 256), dim3(256), 0,
                     stream, in, out);
}